// Round 10
// baseline (5042.575 us; speedup 1.0000x reference)
//
#include <hip/hip_runtime.h>
#include <cstdint>
#include <cstddef>

#define SEQT  512
#define HID   1024
#define G3    3072
#define WSTR  1038   // wlds row stride in shorts (519 dwords, odd -> no 8-way phase)

typedef __attribute__((ext_vector_type(8))) short bf16x8;
typedef __attribute__((ext_vector_type(8))) unsigned short u16x8;
typedef __attribute__((ext_vector_type(4))) float f32x4;

__device__ __forceinline__ float sigm(float x){ return 1.0f/(1.0f+expf(-x)); }
__device__ __forceinline__ float b2f(unsigned short s){ return __uint_as_float(((uint32_t)s)<<16); }
__device__ __forceinline__ unsigned short f2b(float f){
    uint32_t u=__float_as_uint(f);
    return (unsigned short)((u + 0x7FFFu + ((u>>16)&1u))>>16);
}

// ---------------------------------------------------------------------------
// MFMA GEMM (proven since R3). ASRC: 1=f32 reg-staged, 2=bf16 + (1+gate) fuse.
// BSRC: 1=f32 reg-staged. MODE: 0=f32+bias, 1=bf16 tanh(+bias+ctx).
// ---------------------------------------------------------------------------
template<int ASRC, int BSRC, int MODE>
__global__ __launch_bounds__(256) void mfma_gemm(
    const void* __restrict__ Av, const void* __restrict__ Bv,
    const float* __restrict__ bias, const float* __restrict__ ctx,
    const float* __restrict__ gate, void* __restrict__ Cv,
    int N, int K)
{
    __shared__ __align__(16) unsigned short As[128*64];
    __shared__ __align__(16) unsigned short Bs[128*64];
    const int tid = threadIdx.x;
    const int lane = tid & 63;
    const int w = tid >> 6;
    const int wm = w & 1, wn = w >> 1;
    const int m0 = blockIdx.y * 128, n0 = blockIdx.x * 128;

    f32x4 acc[4][4];
#pragma unroll
    for (int i = 0; i < 4; i++)
#pragma unroll
        for (int j = 0; j < 4; j++) acc[i][j] = (f32x4){0.f,0.f,0.f,0.f};

    for (int kt = 0; kt < K; kt += 64) {
        __syncthreads();
        if (ASRC == 1) {
            const float* Af = (const float*)Av;
#pragma unroll
            for (int p = 0; p < 4; p++) {
                const int q = p*256 + tid, row = q>>3, kc = q&7;
                const float* src = Af + (size_t)(m0+row)*K + kt + kc*8;
                float4 u = *(const float4*)src, v = *(const float4*)(src+4);
                __align__(16) unsigned short tmp[8] =
                    {f2b(u.x),f2b(u.y),f2b(u.z),f2b(u.w),f2b(v.x),f2b(v.y),f2b(v.z),f2b(v.w)};
                *(bf16x8*)&As[row*64 + kc*8] = *(const bf16x8*)tmp;
            }
        } else {
            const unsigned short* Ab = (const unsigned short*)Av;
#pragma unroll
            for (int p = 0; p < 4; p++) {
                const int q = p*256 + tid, row = q>>3, kc = q&7;
                const int b = (m0+row) >> 9;
                u16x8 hv = *(const u16x8*)(Ab + (size_t)(m0+row)*K + kt + kc*8);
                const float* gp = gate + (size_t)b*HID + kt + kc*8;
                float4 g0 = *(const float4*)gp, g1 = *(const float4*)(gp+4);
                const float gg[8] = {g0.x,g0.y,g0.z,g0.w,g1.x,g1.y,g1.z,g1.w};
                __align__(16) unsigned short tmp[8];
#pragma unroll
                for (int e = 0; e < 8; e++)
                    tmp[e] = f2b(b2f(hv[e]) * (1.0f + gg[e]));
                *(bf16x8*)&As[row*64 + kc*8] = *(const bf16x8*)tmp;
            }
        }
        {
            const float* Bf = (const float*)Bv;
#pragma unroll
            for (int p = 0; p < 4; p++) {
                const int q = p*256 + tid, row = q>>3, kc = q&7;
                const float* src = Bf + (size_t)(n0+row)*K + kt + kc*8;
                float4 u = *(const float4*)src, v = *(const float4*)(src+4);
                __align__(16) unsigned short tmp[8] =
                    {f2b(u.x),f2b(u.y),f2b(u.z),f2b(u.w),f2b(v.x),f2b(v.y),f2b(v.z),f2b(v.w)};
                *(bf16x8*)&Bs[row*64 + kc*8] = *(const bf16x8*)tmp;
            }
        }
        __syncthreads();
#pragma unroll
        for (int kg = 0; kg < 2; kg++) {
            bf16x8 af[4], bfr[4];
#pragma unroll
            for (int mi = 0; mi < 4; mi++)
                af[mi] = *(const bf16x8*)&As[(wm*64+mi*16+(lane&15))*64 + kg*32 + (lane>>4)*8];
#pragma unroll
            for (int ni = 0; ni < 4; ni++)
                bfr[ni] = *(const bf16x8*)&Bs[(wn*64+ni*16+(lane&15))*64 + kg*32 + (lane>>4)*8];
#pragma unroll
            for (int mi = 0; mi < 4; mi++)
#pragma unroll
                for (int ni = 0; ni < 4; ni++)
                    acc[mi][ni] = __builtin_amdgcn_mfma_f32_16x16x32_bf16(
                        af[mi], bfr[ni], acc[mi][ni], 0, 0, 0);
        }
    }

    const int cl = lane & 15, rg = lane >> 4;
    const int bct = m0 >> 9;
#pragma unroll
    for (int mi = 0; mi < 4; mi++) {
        const int rowb = m0 + wm*64 + mi*16 + rg*4;
#pragma unroll
        for (int ni = 0; ni < 4; ni++) {
            const int col = n0 + wn*64 + ni*16 + cl;
            const float bv = bias[col];
            const float cv = (MODE==1) ? ctx[(size_t)bct*HID + col] : 0.0f;
#pragma unroll
            for (int r = 0; r < 4; r++) {
                float val = acc[mi][ni][r] + bv;
                if (MODE==1) val = tanhf(val + cv);
                const size_t off = (size_t)(rowb+r)*N + col;
                if (MODE==0) ((float*)Cv)[off] = val;
                else ((unsigned short*)Cv)[off] = f2b(val);
            }
        }
    }
}

// ---------------------------------------------------------------------------
__global__ __launch_bounds__(256) void gate_kernel(
    const float* __restrict__ ctx, const float* __restrict__ Wg,
    const float* __restrict__ bg, float* __restrict__ gate)
{
    const int j = blockIdx.x * 256 + threadIdx.x;
    const int b = blockIdx.y;
    const float4* cp = (const float4*)(ctx + (size_t)b * HID);
    const float4* wp = (const float4*)(Wg + (size_t)j * HID);
    float acc = 0.0f;
#pragma unroll 4
    for (int k = 0; k < HID / 4; k++) {
        float4 c = cp[k], w = wp[k];
        acc += c.x * w.x + c.y * w.y + c.z * w.z + c.w * w.w;
    }
    gate[(size_t)b * HID + j] = sigm(acc + bg[j]);
}

// ---------------------------------------------------------------------------
// matvec16: K=512 slice. 16 h-loads forced in-flight via inline asm (the
// compiler provably refuses this at intrinsic level: VGPR stayed 88-92 for
// three rounds). One vmcnt(0), then 16 {ds_read wv, mfma} dataflow-ordered.
// ---------------------------------------------------------------------------
__device__ __forceinline__ void matvec16(const unsigned short* hrow,
                                         const unsigned short* wrow,
                                         f32x4 (&A)[4])
{
    bf16x8 h0,h1,h2,h3,h4,h5,h6,h7,h8,h9,h10,h11,h12,h13,h14,h15;
    asm volatile(
        "global_load_dwordx4 %0, %[a], off\n\t"
        "global_load_dwordx4 %1, %[a], off offset:64\n\t"
        "global_load_dwordx4 %2, %[a], off offset:128\n\t"
        "global_load_dwordx4 %3, %[a], off offset:192\n\t"
        "global_load_dwordx4 %4, %[a], off offset:256\n\t"
        "global_load_dwordx4 %5, %[a], off offset:320\n\t"
        "global_load_dwordx4 %6, %[a], off offset:384\n\t"
        "global_load_dwordx4 %7, %[a], off offset:448\n\t"
        "global_load_dwordx4 %8, %[a], off offset:512\n\t"
        "global_load_dwordx4 %9, %[a], off offset:576\n\t"
        "global_load_dwordx4 %10, %[a], off offset:640\n\t"
        "global_load_dwordx4 %11, %[a], off offset:704\n\t"
        "global_load_dwordx4 %12, %[a], off offset:768\n\t"
        "global_load_dwordx4 %13, %[a], off offset:832\n\t"
        "global_load_dwordx4 %14, %[a], off offset:896\n\t"
        "global_load_dwordx4 %15, %[a], off offset:960\n\t"
        "s_waitcnt vmcnt(0)"
        : "=&v"(h0),"=&v"(h1),"=&v"(h2),"=&v"(h3),
          "=&v"(h4),"=&v"(h5),"=&v"(h6),"=&v"(h7),
          "=&v"(h8),"=&v"(h9),"=&v"(h10),"=&v"(h11),
          "=&v"(h12),"=&v"(h13),"=&v"(h14),"=&v"(h15)
        : [a]"v"(hrow)
        : "memory");
    const bf16x8* wp0  = (const bf16x8*)(wrow);
#define MV_STEP(i, hv) { \
    bf16x8 wv = *(const bf16x8*)(wrow + (i)*32); \
    A[(i)&3] = __builtin_amdgcn_mfma_f32_16x16x32_bf16(hv, wv, A[(i)&3], 0,0,0); }
    MV_STEP(0,h0)  MV_STEP(1,h1)  MV_STEP(2,h2)  MV_STEP(3,h3)
    MV_STEP(4,h4)  MV_STEP(5,h5)  MV_STEP(6,h6)  MV_STEP(7,h7)
    MV_STEP(8,h8)  MV_STEP(9,h9)  MV_STEP(10,h10) MV_STEP(11,h11)
    MV_STEP(12,h12) MV_STEP(13,h13) MV_STEP(14,h14) MV_STEP(15,h15)
#undef MV_STEP
    (void)wp0;
}

// ---------------------------------------------------------------------------
// 4-stage pipelined GRU section (structure proven R7). This round:
// 768 thr = 12 waves = 3 gates x 2 batch-halves x 2 K-halves; asm-forced
// depth-16 h-load pipeline; wlds stride 1038 (odd-dword, bank-clean).
// ---------------------------------------------------------------------------
__global__ __launch_bounds__(768, 1) void gru_pipe(
    const float* __restrict__ Wih0, const float* __restrict__ Whh0,
    const float* __restrict__ bih0, const float* __restrict__ bhh0,
    const float* __restrict__ Wih1, const float* __restrict__ Whh1,
    const float* __restrict__ bih1, const float* __restrict__ bhh1,
    const unsigned short* __restrict__ mixed,   // [B*T][H] bf16
    unsigned short* __restrict__ h1,
    unsigned short* __restrict__ h2,
    unsigned short* __restrict__ xgs0,          // [64][8][32][48] bf16
    unsigned short* __restrict__ xgs1,
    unsigned int* __restrict__ flags)           // 4 sets x 64 x 16 u32
{
    __shared__ __align__(16) unsigned short wlds[48*WSTR];
    __shared__ float sc[3][2][32][17];
    __shared__ uint32_t hlds[32][8];
    const int tid = threadIdx.x;
    const int lane = tid & 63;
    const int w = tid >> 6;                 // 0..11
    const int bid = blockIdx.x;
    const int role = bid >> 6, rb = bid & 63;
    const int j0 = rb * 16;
    const int g  = w >> 2;                  // gate 0..2
    const int mh = (w >> 1) & 1;            // batch half
    const int kh = w & 1;                   // K half
    const int cl = lane & 15, kq = lane >> 4;

    unsigned int* fset[4] = { flags, flags + 1024, flags + 2048, flags + 3072 };

    // stage this role's 48-row weight slice f32 -> bf16 LDS
    const float* Wsrc = (role == 0) ? Wih0 : (role == 1) ? Whh0
                      : (role == 2) ? Wih1 : Whh1;
    for (int i = tid; i < 48*128; i += 768) {
        const int rr = i >> 7, kc = i & 127;
        const int grow = (rr>>4)*1024 + j0 + (rr&15);
        const float* src = Wsrc + (size_t)grow*1024 + kc*8;
        float4 u = *(const float4*)src, v = *(const float4*)(src+4);
        __align__(16) unsigned short tmp[8] =
            {f2b(u.x),f2b(u.y),f2b(u.z),f2b(u.w),f2b(v.x),f2b(v.y),f2b(v.z),f2b(v.w)};
        *(bf16x8*)&wlds[rr*WSTR + kc*8] = *(const bf16x8*)tmp;
    }
    __syncthreads();

    const unsigned short* wrow = &wlds[(g*16+cl)*WSTR + kh*512 + kq*8];

    if ((role & 1) == 0) {
        // ---------------- producer: xg = Wih @ hsrc[t] -------------------
        const unsigned short* hsrc = (role == 0) ? mixed : h1;
        unsigned short* xgs = ((role == 0) ? xgs0 : xgs1) + (size_t)rb*8*32*48;
        const unsigned int* waitin = (role == 2) ? fset[1] : nullptr; // P1 waits R0
        const unsigned int* bp     = (role == 0) ? fset[1] : fset[3]; // consumer R
        unsigned int* myflag = &fset[role][rb*16];

        for (int t = 0; t < SEQT; t++) {
            if (w == 0 && waitin) {
                while (__hip_atomic_load(&waitin[lane*16], __ATOMIC_RELAXED,
                                         __HIP_MEMORY_SCOPE_AGENT) < (unsigned)(t+1)) {}
            }
            if (w == 1 && t >= 8) {
                while (__hip_atomic_load(&bp[lane*16], __ATOMIC_RELAXED,
                                         __HIP_MEMORY_SCOPE_AGENT) < (unsigned)(t-7)) {}
            }
            __syncthreads();

            f32x4 A[4];
#pragma unroll
            for (int i = 0; i < 4; i++) A[i] = (f32x4){0.f,0.f,0.f,0.f};
            const unsigned short* hrow =
                hsrc + ((size_t)(mh*16+cl)*SEQT + t)*HID + kh*512 + kq*8;
            matvec16(hrow, wrow, A);
            f32x4 av = (A[0] + A[1]) + (A[2] + A[3]);
#pragma unroll
            for (int r = 0; r < 4; r++)
                sc[g][kh][mh*16 + kq*4 + r][cl] = av[r];
            __syncthreads();

            if (tid < 192) {
                const int b = tid / 6, c16 = (tid % 6) * 8;
                unsigned short v[8];
#pragma unroll
                for (int k = 0; k < 8; k++) {
                    const int col = c16 + k;
                    v[k] = f2b(sc[col >> 4][0][b][col & 15]
                             + sc[col >> 4][1][b][col & 15]);
                }
                const uint64_t lo = (uint64_t)v[0] | ((uint64_t)v[1]<<16)
                                  | ((uint64_t)v[2]<<32) | ((uint64_t)v[3]<<48);
                const uint64_t hi = (uint64_t)v[4] | ((uint64_t)v[5]<<16)
                                  | ((uint64_t)v[6]<<32) | ((uint64_t)v[7]<<48);
                uint64_t* dst = (uint64_t*)(xgs + (((size_t)(t&7)*32 + b)*48 + c16));
                __hip_atomic_store(dst,   lo, __ATOMIC_RELAXED, __HIP_MEMORY_SCOPE_AGENT);
                __hip_atomic_store(dst+1, hi, __ATOMIC_RELAXED, __HIP_MEMORY_SCOPE_AGENT);
            }
            asm volatile("s_waitcnt vmcnt(0)" ::: "memory");
            __syncthreads();
            if (tid == 0)
                __hip_atomic_store(myflag, (unsigned)(t+1),
                                   __ATOMIC_RELAXED, __HIP_MEMORY_SCOPE_AGENT);
        }
    } else {
        // ---------------- recurrent: h[t] from xgs[t] + Whh@h[t-1] -------
        const unsigned short* xgs = ((role == 1) ? xgs0 : xgs1) + (size_t)rb*8*32*48;
        unsigned short* hdst = (role == 1) ? h1 : h2;
        const float* bih = (role == 1) ? bih0 : bih1;
        const float* bhh = (role == 1) ? bhh0 : bhh1;
        const unsigned int* peers = fset[role];
        const unsigned int* prodf = &fset[role-1][rb*16];
        unsigned int* myflag = &fset[role][rb*16];

        const int fb = tid >> 3;
        const int fj = (tid & 7) * 2;
        float hp0 = 0.f, hp1 = 0.f;
        float br0=0,br1=0,bz0=0,bz1=0,bni0=0,bni1=0,bnh0=0,bnh1=0;
        if (tid < 256) {
            br0 = bih[j0+fj]        + bhh[j0+fj];
            br1 = bih[j0+fj+1]      + bhh[j0+fj+1];
            bz0 = bih[HID+j0+fj]    + bhh[HID+j0+fj];
            bz1 = bih[HID+j0+fj+1]  + bhh[HID+j0+fj+1];
            bni0 = bih[2*HID+j0+fj];   bni1 = bih[2*HID+j0+fj+1];
            bnh0 = bhh[2*HID+j0+fj];   bnh1 = bhh[2*HID+j0+fj+1];
        }

        for (int t = 0; t < SEQT; t++) {
            if (w == 0 && t > 0) {
                while (__hip_atomic_load(&peers[lane*16], __ATOMIC_RELAXED,
                                         __HIP_MEMORY_SCOPE_AGENT) < (unsigned)t) {}
            }
            if (w == 2 && lane == 0) {
                while (__hip_atomic_load(prodf, __ATOMIC_RELAXED,
                                         __HIP_MEMORY_SCOPE_AGENT) < (unsigned)(t+1)) {}
            }
            __syncthreads();

            uint32_t xr2=0, xz2=0, xn2=0;
            if (tid < 256) {
                const unsigned short* xp = xgs + ((size_t)(t&7)*32 + fb)*48;
                xr2 = __hip_atomic_load((const unsigned int*)(xp + fj),
                                        __ATOMIC_RELAXED, __HIP_MEMORY_SCOPE_AGENT);
                xz2 = __hip_atomic_load((const unsigned int*)(xp + 16 + fj),
                                        __ATOMIC_RELAXED, __HIP_MEMORY_SCOPE_AGENT);
                xn2 = __hip_atomic_load((const unsigned int*)(xp + 32 + fj),
                                        __ATOMIC_RELAXED, __HIP_MEMORY_SCOPE_AGENT);
            }

            f32x4 A[4];
#pragma unroll
            for (int i = 0; i < 4; i++) A[i] = (f32x4){0.f,0.f,0.f,0.f};
            if (t > 0) {
                const unsigned short* hrow =
                    hdst + ((size_t)(mh*16+cl)*SEQT + (t-1))*HID + kh*512 + kq*8;
                matvec16(hrow, wrow, A);
            }
            f32x4 av = (A[0] + A[1]) + (A[2] + A[3]);
#pragma unroll
            for (int r = 0; r < 4; r++)
                sc[g][kh][mh*16 + kq*4 + r][cl] = av[r];
            __syncthreads();

            if (tid < 256) {
                const float sr0 = sc[0][0][fb][fj]   + sc[0][1][fb][fj];
                const float sr1 = sc[0][0][fb][fj+1] + sc[0][1][fb][fj+1];
                const float sz0 = sc[1][0][fb][fj]   + sc[1][1][fb][fj];
                const float sz1 = sc[1][0][fb][fj+1] + sc[1][1][fb][fj+1];
                const float sn0 = sc[2][0][fb][fj]   + sc[2][1][fb][fj];
                const float sn1 = sc[2][0][fb][fj+1] + sc[2][1][fb][fj+1];
                const float r0 = sigm(b2f((unsigned short)(xr2 & 0xFFFF)) + sr0 + br0);
                const float r1 = sigm(b2f((unsigned short)(xr2 >> 16))    + sr1 + br1);
                const float z0 = sigm(b2f((unsigned short)(xz2 & 0xFFFF)) + sz0 + bz0);
                const float z1 = sigm(b2f((unsigned short)(xz2 >> 16))    + sz1 + bz1);
                const float n0 = tanhf(b2f((unsigned short)(xn2 & 0xFFFF)) + bni0
                                       + r0*(sn0 + bnh0));
                const float n1 = tanhf(b2f((unsigned short)(xn2 >> 16))    + bni1
                                       + r1*(sn1 + bnh1));
                const float h0 = (1.0f - z0)*n0 + z0*hp0;
                const float h1v = (1.0f - z1)*n1 + z1*hp1;
                hp0 = h0; hp1 = h1v;
                hlds[fb][fj >> 1] = (uint32_t)f2b(h0) | ((uint32_t)f2b(h1v) << 16);
            }
            __syncthreads();

            if (w == 11) {
                const int pb = lane >> 1, ph = lane & 1;
                const uint32_t v0 = hlds[pb][ph*4 + 0];
                const uint32_t v1 = hlds[pb][ph*4 + 1];
                const uint32_t v2 = hlds[pb][ph*4 + 2];
                const uint32_t v3 = hlds[pb][ph*4 + 3];
                uint64_t* dst = (uint64_t*)(hdst + ((size_t)pb*SEQT + t)*HID + j0 + ph*8);
                __hip_atomic_store(dst,   (uint64_t)v0 | ((uint64_t)v1 << 32),
                                   __ATOMIC_RELAXED, __HIP_MEMORY_SCOPE_AGENT);
                __hip_atomic_store(dst+1, (uint64_t)v2 | ((uint64_t)v3 << 32),
                                   __ATOMIC_RELAXED, __HIP_MEMORY_SCOPE_AGENT);
                asm volatile("s_waitcnt vmcnt(0)" ::: "memory");
                if (lane == 0)
                    __hip_atomic_store(myflag, (unsigned)(t+1),
                                       __ATOMIC_RELAXED, __HIP_MEMORY_SCOPE_AGENT);
            }
        }
    }
}

// ---------------------------------------------------------------------------
__global__ __launch_bounds__(256) void diag_kernel(float* __restrict__ out,
                                                   int n, float code)
{
    for (int i = blockIdx.x * 256 + threadIdx.x; i < n; i += gridDim.x * 256)
        out[i] = (i == 0) ? code : 0.0f;
}

// ---------------------------------------------------------------------------
extern "C" void kernel_launch(void* const* d_in, const int* in_sizes, int n_in,
                              void* d_out, int out_size, void* d_ws, size_t ws_size,
                              hipStream_t stream)
{
    const float* x      = (const float*)d_in[0];
    const float* ctx    = (const float*)d_in[1];
    const float* W_in   = (const float*)d_in[2];
    const float* b_in   = (const float*)d_in[3];
    const float* Wih0   = (const float*)d_in[4];
    const float* Whh0   = (const float*)d_in[5];
    const float* bih0   = (const float*)d_in[6];
    const float* bhh0   = (const float*)d_in[7];
    const float* Wih1   = (const float*)d_in[8];
    const float* Whh1   = (const float*)d_in[9];
    const float* bih1   = (const float*)d_in[10];
    const float* bhh1   = (const float*)d_in[11];
    const float* W_out  = (const float*)d_in[12];
    const float* b_out  = (const float*)d_in[13];
    const float* W_gate = (const float*)d_in[14];
    const float* b_gate = (const float*)d_in[15];
    float* out = (float*)d_out;

    const size_t MX = (size_t)16384 * 1024 * 2;
    const size_t XS = (size_t)64 * 8 * 32 * 48 * 2;
    const size_t GT = (size_t)32 * 1024 * 4;
    const size_t FL = 16384;
    const size_t need = 3*MX + 2*XS + GT + FL;

    if (ws_size < need) {
        diag_kernel<<<2048, 256, 0, stream>>>(out, out_size, (float)(ws_size >> 20));
        return;
    }

    char* ws = (char*)d_ws;
    unsigned short* mixed = (unsigned short*)ws;
    unsigned short* h1    = (unsigned short*)(ws + MX);
    unsigned short* h2    = (unsigned short*)(ws + 2*MX);
    unsigned short* xgs0  = (unsigned short*)(ws + 3*MX);
    unsigned short* xgs1  = (unsigned short*)(ws + 3*MX + XS);
    float*          gate  = (float*)(ws + 3*MX + 2*XS);
    unsigned int*   flags = (unsigned int*)(ws + 3*MX + 2*XS + GT);

    hipMemsetAsync(flags, 0, FL, stream);
    gate_kernel<<<dim3(4, 32), 256, 0, stream>>>(ctx, W_gate, b_gate, gate);

    // mixed = tanh(x @ W_in^T + b_in + ctx[b]) -> bf16
    mfma_gemm<1, 1, 1><<<dim3(8, 128), 256, 0, stream>>>(
        x, W_in, b_in, ctx, nullptr, mixed, 1024, 1024);

    // 4-stage pipelined GRU section
    gru_pipe<<<256, 768, 0, stream>>>(
        Wih0, Whh0, bih0, bhh0, Wih1, Whh1, bih1, bhh1,
        mixed, h1, h2, xgs0, xgs1, flags);

    // out = (h2 * (1+gate)) @ W_out^T + b_out -> f32
    mfma_gemm<2, 1, 0><<<dim3(8, 128), 256, 0, stream>>>(
        h2, W_out, b_out, nullptr, gate, out, 1024, 1024);
}

// Round 11
// 4478.525 us; speedup vs baseline: 1.1259x; 1.1259x over previous
//
#include <hip/hip_runtime.h>
#include <cstdint>
#include <cstddef>

#define SEQT  512
#define HID   1024
#define G3    3072
#define WSTR  1038   // wlds row stride in shorts (519 dwords, odd -> banks spread)
#define RING  32     // xgs ring depth
#define FSTR  32     // flag stride in u32 (128 B -> one flag per cacheline)

typedef __attribute__((ext_vector_type(8))) short bf16x8;
typedef __attribute__((ext_vector_type(8))) unsigned short u16x8;
typedef __attribute__((ext_vector_type(4))) float f32x4;

__device__ __forceinline__ float sigm(float x){ return 1.0f/(1.0f+expf(-x)); }
__device__ __forceinline__ float b2f(unsigned short s){ return __uint_as_float(((uint32_t)s)<<16); }
__device__ __forceinline__ unsigned short f2b(float f){
    uint32_t u=__float_as_uint(f);
    return (unsigned short)((u + 0x7FFFu + ((u>>16)&1u))>>16);
}

// ---------------------------------------------------------------------------
// MFMA GEMM (proven since R3). ASRC: 1=f32 reg-staged, 2=bf16 + (1+gate) fuse.
// BSRC: 1=f32 reg-staged. MODE: 0=f32+bias, 1=bf16 tanh(+bias+ctx).
// ---------------------------------------------------------------------------
template<int ASRC, int BSRC, int MODE>
__global__ __launch_bounds__(256) void mfma_gemm(
    const void* __restrict__ Av, const void* __restrict__ Bv,
    const float* __restrict__ bias, const float* __restrict__ ctx,
    const float* __restrict__ gate, void* __restrict__ Cv,
    int N, int K)
{
    __shared__ __align__(16) unsigned short As[128*64];
    __shared__ __align__(16) unsigned short Bs[128*64];
    const int tid = threadIdx.x;
    const int lane = tid & 63;
    const int w = tid >> 6;
    const int wm = w & 1, wn = w >> 1;
    const int m0 = blockIdx.y * 128, n0 = blockIdx.x * 128;

    f32x4 acc[4][4];
#pragma unroll
    for (int i = 0; i < 4; i++)
#pragma unroll
        for (int j = 0; j < 4; j++) acc[i][j] = (f32x4){0.f,0.f,0.f,0.f};

    for (int kt = 0; kt < K; kt += 64) {
        __syncthreads();
        if (ASRC == 1) {
            const float* Af = (const float*)Av;
#pragma unroll
            for (int p = 0; p < 4; p++) {
                const int q = p*256 + tid, row = q>>3, kc = q&7;
                const float* src = Af + (size_t)(m0+row)*K + kt + kc*8;
                float4 u = *(const float4*)src, v = *(const float4*)(src+4);
                __align__(16) unsigned short tmp[8] =
                    {f2b(u.x),f2b(u.y),f2b(u.z),f2b(u.w),f2b(v.x),f2b(v.y),f2b(v.z),f2b(v.w)};
                *(bf16x8*)&As[row*64 + kc*8] = *(const bf16x8*)tmp;
            }
        } else {
            const unsigned short* Ab = (const unsigned short*)Av;
#pragma unroll
            for (int p = 0; p < 4; p++) {
                const int q = p*256 + tid, row = q>>3, kc = q&7;
                const int b = (m0+row) >> 9;
                u16x8 hv = *(const u16x8*)(Ab + (size_t)(m0+row)*K + kt + kc*8);
                const float* gp = gate + (size_t)b*HID + kt + kc*8;
                float4 g0 = *(const float4*)gp, g1 = *(const float4*)(gp+4);
                const float gg[8] = {g0.x,g0.y,g0.z,g0.w,g1.x,g1.y,g1.z,g1.w};
                __align__(16) unsigned short tmp[8];
#pragma unroll
                for (int e = 0; e < 8; e++)
                    tmp[e] = f2b(b2f(hv[e]) * (1.0f + gg[e]));
                *(bf16x8*)&As[row*64 + kc*8] = *(const bf16x8*)tmp;
            }
        }
        {
            const float* Bf = (const float*)Bv;
#pragma unroll
            for (int p = 0; p < 4; p++) {
                const int q = p*256 + tid, row = q>>3, kc = q&7;
                const float* src = Bf + (size_t)(n0+row)*K + kt + kc*8;
                float4 u = *(const float4*)src, v = *(const float4*)(src+4);
                __align__(16) unsigned short tmp[8] =
                    {f2b(u.x),f2b(u.y),f2b(u.z),f2b(u.w),f2b(v.x),f2b(v.y),f2b(v.z),f2b(v.w)};
                *(bf16x8*)&Bs[row*64 + kc*8] = *(const bf16x8*)tmp;
            }
        }
        __syncthreads();
#pragma unroll
        for (int kg = 0; kg < 2; kg++) {
            bf16x8 af[4], bfr[4];
#pragma unroll
            for (int mi = 0; mi < 4; mi++)
                af[mi] = *(const bf16x8*)&As[(wm*64+mi*16+(lane&15))*64 + kg*32 + (lane>>4)*8];
#pragma unroll
            for (int ni = 0; ni < 4; ni++)
                bfr[ni] = *(const bf16x8*)&Bs[(wn*64+ni*16+(lane&15))*64 + kg*32 + (lane>>4)*8];
#pragma unroll
            for (int mi = 0; mi < 4; mi++)
#pragma unroll
                for (int ni = 0; ni < 4; ni++)
                    acc[mi][ni] = __builtin_amdgcn_mfma_f32_16x16x32_bf16(
                        af[mi], bfr[ni], acc[mi][ni], 0, 0, 0);
        }
    }

    const int cl = lane & 15, rg = lane >> 4;
    const int bct = m0 >> 9;
#pragma unroll
    for (int mi = 0; mi < 4; mi++) {
        const int rowb = m0 + wm*64 + mi*16 + rg*4;
#pragma unroll
        for (int ni = 0; ni < 4; ni++) {
            const int col = n0 + wn*64 + ni*16 + cl;
            const float bv = bias[col];
            const float cv = (MODE==1) ? ctx[(size_t)bct*HID + col] : 0.0f;
#pragma unroll
            for (int r = 0; r < 4; r++) {
                float val = acc[mi][ni][r] + bv;
                if (MODE==1) val = tanhf(val + cv);
                const size_t off = (size_t)(rowb+r)*N + col;
                if (MODE==0) ((float*)Cv)[off] = val;
                else ((unsigned short*)Cv)[off] = f2b(val);
            }
        }
    }
}

// ---------------------------------------------------------------------------
__global__ __launch_bounds__(256) void gate_kernel(
    const float* __restrict__ ctx, const float* __restrict__ Wg,
    const float* __restrict__ bg, float* __restrict__ gate)
{
    const int j = blockIdx.x * 256 + threadIdx.x;
    const int b = blockIdx.y;
    const float4* cp = (const float4*)(ctx + (size_t)b * HID);
    const float4* wp = (const float4*)(Wg + (size_t)j * HID);
    float acc = 0.0f;
#pragma unroll 4
    for (int k = 0; k < HID / 4; k++) {
        float4 c = cp[k], w = wp[k];
        acc += c.x * w.x + c.y * w.y + c.z * w.z + c.w * w.w;
    }
    gate[(size_t)b * HID + j] = sigm(acc + bg[j]);
}

// ---------------------------------------------------------------------------
// matvec32: R7's proven chained form (best measured: 4.31 ms pipe).
// ---------------------------------------------------------------------------
__device__ __forceinline__ void matvec32(const unsigned short* __restrict__ hrow,
                                         const unsigned short* __restrict__ wrow,
                                         f32x4 (&A)[4])
{
#pragma unroll
    for (int kg = 0; kg < 32; kg += 4) {
        bf16x8 h0 = *(const bf16x8*)(hrow + (size_t)(kg+0)*32);
        bf16x8 w0 = *(const bf16x8*)(wrow + (size_t)(kg+0)*32);
        A[0] = __builtin_amdgcn_mfma_f32_16x16x32_bf16(h0, w0, A[0], 0,0,0);
        bf16x8 h1 = *(const bf16x8*)(hrow + (size_t)(kg+1)*32);
        bf16x8 w1 = *(const bf16x8*)(wrow + (size_t)(kg+1)*32);
        A[1] = __builtin_amdgcn_mfma_f32_16x16x32_bf16(h1, w1, A[1], 0,0,0);
        bf16x8 h2 = *(const bf16x8*)(hrow + (size_t)(kg+2)*32);
        bf16x8 w2 = *(const bf16x8*)(wrow + (size_t)(kg+2)*32);
        A[2] = __builtin_amdgcn_mfma_f32_16x16x32_bf16(h2, w2, A[2], 0,0,0);
        bf16x8 h3 = *(const bf16x8*)(hrow + (size_t)(kg+3)*32);
        bf16x8 w3 = *(const bf16x8*)(wrow + (size_t)(kg+3)*32);
        A[3] = __builtin_amdgcn_mfma_f32_16x16x32_bf16(h3, w3, A[3], 0,0,0);
    }
}

__device__ __forceinline__ void poll_ge(const unsigned int* p, unsigned int tgt)
{
    while (__hip_atomic_load(p, __ATOMIC_RELAXED, __HIP_MEMORY_SCOPE_AGENT) < tgt)
        __builtin_amdgcn_s_sleep(2);   // backoff: cut poll-rate ~2-3x
}

// ---------------------------------------------------------------------------
// 4-stage pipelined GRU section (R7 structure). This round: congestion cuts —
// 128B-strided flags, sleep-backoff polls, 32-deep xgs ring with batched
// back-pressure (P polls consumer flag only every 8 steps), WSTR bank fix.
// ---------------------------------------------------------------------------
__global__ __launch_bounds__(384, 1) void gru_pipe(
    const float* __restrict__ Wih0, const float* __restrict__ Whh0,
    const float* __restrict__ bih0, const float* __restrict__ bhh0,
    const float* __restrict__ Wih1, const float* __restrict__ Whh1,
    const float* __restrict__ bih1, const float* __restrict__ bhh1,
    const unsigned short* __restrict__ mixed,   // [B*T][H] bf16
    unsigned short* __restrict__ h1,
    unsigned short* __restrict__ h2,
    unsigned short* __restrict__ xgs0,          // [64][RING][32][48] bf16
    unsigned short* __restrict__ xgs1,
    unsigned int* __restrict__ flags)           // 4 sets x 64 x FSTR u32
{
    __shared__ __align__(16) unsigned short wlds[48*WSTR];
    __shared__ float sc[3][32][17];
    __shared__ uint32_t hlds[32][8];
    const int tid = threadIdx.x;
    const int lane = tid & 63;
    const int w = tid >> 6;
    const int bid = blockIdx.x;
    const int role = bid >> 6, rb = bid & 63;
    const int j0 = rb * 16;
    const int mh = w & 1, g = w >> 1;
    const int cl = lane & 15, kq = lane >> 4;

    unsigned int* fset[4] = { flags, flags + 64*FSTR, flags + 128*FSTR, flags + 192*FSTR };

    // stage this role's 48-row weight slice f32 -> bf16 LDS
    const float* Wsrc = (role == 0) ? Wih0 : (role == 1) ? Whh0
                      : (role == 2) ? Wih1 : Whh1;
    for (int i = tid; i < 48*128; i += 384) {
        const int rr = i >> 7, kc = i & 127;
        const int grow = (rr>>4)*1024 + j0 + (rr&15);
        const float* src = Wsrc + (size_t)grow*1024 + kc*8;
        float4 u = *(const float4*)src, v = *(const float4*)(src+4);
        __align__(16) unsigned short tmp[8] =
            {f2b(u.x),f2b(u.y),f2b(u.z),f2b(u.w),f2b(v.x),f2b(v.y),f2b(v.z),f2b(v.w)};
        *(bf16x8*)&wlds[rr*WSTR + kc*8] = *(const bf16x8*)tmp;
    }
    __syncthreads();

    const unsigned short* wrow = &wlds[(g*16+cl)*WSTR + kq*8];

    if ((role & 1) == 0) {
        // ---------------- producer: xg = Wih @ hsrc[t] -------------------
        const unsigned short* hsrc = (role == 0) ? mixed : h1;
        unsigned short* xgs = ((role == 0) ? xgs0 : xgs1) + (size_t)rb*RING*32*48;
        const unsigned int* waitin = (role == 2) ? fset[1] : nullptr; // P1 waits R0
        const unsigned int* bp     = (role == 0) ? fset[1] : fset[3]; // consumer R
        unsigned int* myflag = &fset[role][rb*FSTR];

        for (int t = 0; t < SEQT; t++) {
            if (w == 0 && waitin)
                poll_ge(&waitin[lane*FSTR], (unsigned)(t+1));
            // batched back-pressure: slot reuse needs bp >= t-31; checking
            // every 8 steps with margin: at t%8==0 require bp >= t-24.
            if (w == 1 && t >= RING && (t & 7) == 0)
                poll_ge(&bp[lane*FSTR], (unsigned)(t - 24));
            __syncthreads();

            f32x4 A[4];
#pragma unroll
            for (int i = 0; i < 4; i++) A[i] = (f32x4){0.f,0.f,0.f,0.f};
            const unsigned short* hrow =
                hsrc + ((size_t)(mh*16+cl)*SEQT + t)*HID + kq*8;
            matvec32(hrow, wrow, A);
            f32x4 av = (A[0] + A[1]) + (A[2] + A[3]);
#pragma unroll
            for (int r = 0; r < 4; r++)
                sc[g][mh*16 + kq*4 + r][cl] = av[r];
            __syncthreads();

            if (tid < 192) {
                const int b = tid / 6, c16 = (tid % 6) * 8;
                unsigned short v[8];
#pragma unroll
                for (int k = 0; k < 8; k++) {
                    const int col = c16 + k;
                    v[k] = f2b(sc[col >> 4][b][col & 15]);
                }
                const uint64_t lo = (uint64_t)v[0] | ((uint64_t)v[1]<<16)
                                  | ((uint64_t)v[2]<<32) | ((uint64_t)v[3]<<48);
                const uint64_t hi = (uint64_t)v[4] | ((uint64_t)v[5]<<16)
                                  | ((uint64_t)v[6]<<32) | ((uint64_t)v[7]<<48);
                uint64_t* dst = (uint64_t*)(xgs + (((size_t)(t & (RING-1))*32 + b)*48 + c16));
                __hip_atomic_store(dst,   lo, __ATOMIC_RELAXED, __HIP_MEMORY_SCOPE_AGENT);
                __hip_atomic_store(dst+1, hi, __ATOMIC_RELAXED, __HIP_MEMORY_SCOPE_AGENT);
            }
            asm volatile("s_waitcnt vmcnt(0)" ::: "memory");
            __syncthreads();
            if (tid == 0)
                __hip_atomic_store(myflag, (unsigned)(t+1),
                                   __ATOMIC_RELAXED, __HIP_MEMORY_SCOPE_AGENT);
        }
    } else {
        // ---------------- recurrent: h[t] from xgs[t] + Whh@h[t-1] -------
        const unsigned short* xgs = ((role == 1) ? xgs0 : xgs1) + (size_t)rb*RING*32*48;
        unsigned short* hdst = (role == 1) ? h1 : h2;
        const float* bih = (role == 1) ? bih0 : bih1;
        const float* bhh = (role == 1) ? bhh0 : bhh1;
        const unsigned int* peers = fset[role];
        const unsigned int* prodf = &fset[role-1][rb*FSTR];
        unsigned int* myflag = &fset[role][rb*FSTR];

        const int fb = tid >> 3;
        const int fj = (tid & 7) * 2;
        float hp0 = 0.f, hp1 = 0.f;
        float br0=0,br1=0,bz0=0,bz1=0,bni0=0,bni1=0,bnh0=0,bnh1=0;
        if (tid < 256) {
            br0 = bih[j0+fj]        + bhh[j0+fj];
            br1 = bih[j0+fj+1]      + bhh[j0+fj+1];
            bz0 = bih[HID+j0+fj]    + bhh[HID+j0+fj];
            bz1 = bih[HID+j0+fj+1]  + bhh[HID+j0+fj+1];
            bni0 = bih[2*HID+j0+fj];   bni1 = bih[2*HID+j0+fj+1];
            bnh0 = bhh[2*HID+j0+fj];   bnh1 = bhh[2*HID+j0+fj+1];
        }

        for (int t = 0; t < SEQT; t++) {
            if (w == 0 && t > 0)
                poll_ge(&peers[lane*FSTR], (unsigned)t);
            if (w == 2 && lane == 0)
                poll_ge(prodf, (unsigned)(t+1));
            __syncthreads();

            uint32_t xr2=0, xz2=0, xn2=0;
            if (tid < 256) {
                const unsigned short* xp = xgs + ((size_t)(t & (RING-1))*32 + fb)*48;
                xr2 = __hip_atomic_load((const unsigned int*)(xp + fj),
                                        __ATOMIC_RELAXED, __HIP_MEMORY_SCOPE_AGENT);
                xz2 = __hip_atomic_load((const unsigned int*)(xp + 16 + fj),
                                        __ATOMIC_RELAXED, __HIP_MEMORY_SCOPE_AGENT);
                xn2 = __hip_atomic_load((const unsigned int*)(xp + 32 + fj),
                                        __ATOMIC_RELAXED, __HIP_MEMORY_SCOPE_AGENT);
            }

            f32x4 A[4];
#pragma unroll
            for (int i = 0; i < 4; i++) A[i] = (f32x4){0.f,0.f,0.f,0.f};
            if (t > 0) {
                const unsigned short* hrow =
                    hdst + ((size_t)(mh*16+cl)*SEQT + (t-1))*HID + kq*8;
                matvec32(hrow, wrow, A);
            }
            f32x4 av = (A[0] + A[1]) + (A[2] + A[3]);
#pragma unroll
            for (int r = 0; r < 4; r++)
                sc[g][mh*16 + kq*4 + r][cl] = av[r];
            __syncthreads();

            if (tid < 256) {
                const float r0 = sigm(b2f((unsigned short)(xr2 & 0xFFFF)) + sc[0][fb][fj]   + br0);
                const float r1 = sigm(b2f((unsigned short)(xr2 >> 16))    + sc[0][fb][fj+1] + br1);
                const float z0 = sigm(b2f((unsigned short)(xz2 & 0xFFFF)) + sc[1][fb][fj]   + bz0);
                const float z1 = sigm(b2f((unsigned short)(xz2 >> 16))    + sc[1][fb][fj+1] + bz1);
                const float n0 = tanhf(b2f((unsigned short)(xn2 & 0xFFFF)) + bni0
                                       + r0*(sc[2][fb][fj]   + bnh0));
                const float n1 = tanhf(b2f((unsigned short)(xn2 >> 16))    + bni1
                                       + r1*(sc[2][fb][fj+1] + bnh1));
                const float h0 = (1.0f - z0)*n0 + z0*hp0;
                const float h1v = (1.0f - z1)*n1 + z1*hp1;
                hp0 = h0; hp1 = h1v;
                hlds[fb][fj >> 1] = (uint32_t)f2b(h0) | ((uint32_t)f2b(h1v) << 16);
            }
            __syncthreads();

            if (w == 5) {
                const int pb = lane >> 1, ph = lane & 1;
                const uint32_t v0 = hlds[pb][ph*4 + 0];
                const uint32_t v1 = hlds[pb][ph*4 + 1];
                const uint32_t v2 = hlds[pb][ph*4 + 2];
                const uint32_t v3 = hlds[pb][ph*4 + 3];
                uint64_t* dst = (uint64_t*)(hdst + ((size_t)pb*SEQT + t)*HID + j0 + ph*8);
                __hip_atomic_store(dst,   (uint64_t)v0 | ((uint64_t)v1 << 32),
                                   __ATOMIC_RELAXED, __HIP_MEMORY_SCOPE_AGENT);
                __hip_atomic_store(dst+1, (uint64_t)v2 | ((uint64_t)v3 << 32),
                                   __ATOMIC_RELAXED, __HIP_MEMORY_SCOPE_AGENT);
                asm volatile("s_waitcnt vmcnt(0)" ::: "memory");
                if (lane == 0)
                    __hip_atomic_store(myflag, (unsigned)(t+1),
                                       __ATOMIC_RELAXED, __HIP_MEMORY_SCOPE_AGENT);
            }
        }
    }
}

// ---------------------------------------------------------------------------
__global__ __launch_bounds__(256) void diag_kernel(float* __restrict__ out,
                                                   int n, float code)
{
    for (int i = blockIdx.x * 256 + threadIdx.x; i < n; i += gridDim.x * 256)
        out[i] = (i == 0) ? code : 0.0f;
}

// ---------------------------------------------------------------------------
extern "C" void kernel_launch(void* const* d_in, const int* in_sizes, int n_in,
                              void* d_out, int out_size, void* d_ws, size_t ws_size,
                              hipStream_t stream)
{
    const float* x      = (const float*)d_in[0];
    const float* ctx    = (const float*)d_in[1];
    const float* W_in   = (const float*)d_in[2];
    const float* b_in   = (const float*)d_in[3];
    const float* Wih0   = (const float*)d_in[4];
    const float* Whh0   = (const float*)d_in[5];
    const float* bih0   = (const float*)d_in[6];
    const float* bhh0   = (const float*)d_in[7];
    const float* Wih1   = (const float*)d_in[8];
    const float* Whh1   = (const float*)d_in[9];
    const float* bih1   = (const float*)d_in[10];
    const float* bhh1   = (const float*)d_in[11];
    const float* W_out  = (const float*)d_in[12];
    const float* b_out  = (const float*)d_in[13];
    const float* W_gate = (const float*)d_in[14];
    const float* b_gate = (const float*)d_in[15];
    float* out = (float*)d_out;

    const size_t MX = (size_t)16384 * 1024 * 2;                 // 32 MiB
    const size_t XS = (size_t)64 * RING * 32 * 48 * 2;          // 6 MiB
    const size_t GT = (size_t)32 * 1024 * 4;
    const size_t FL = (size_t)4 * 64 * FSTR * 4;                // 32 KiB
    const size_t need = 3*MX + 2*XS + GT + FL;

    if (ws_size < need) {
        diag_kernel<<<2048, 256, 0, stream>>>(out, out_size, (float)(ws_size >> 20));
        return;
    }

    char* ws = (char*)d_ws;
    unsigned short* mixed = (unsigned short*)ws;
    unsigned short* h1    = (unsigned short*)(ws + MX);
    unsigned short* h2    = (unsigned short*)(ws + 2*MX);
    unsigned short* xgs0  = (unsigned short*)(ws + 3*MX);
    unsigned short* xgs1  = (unsigned short*)(ws + 3*MX + XS);
    float*          gate  = (float*)(ws + 3*MX + 2*XS);
    unsigned int*   flags = (unsigned int*)(ws + 3*MX + 2*XS + GT);

    hipMemsetAsync(flags, 0, FL, stream);
    gate_kernel<<<dim3(4, 32), 256, 0, stream>>>(ctx, W_gate, b_gate, gate);

    // mixed = tanh(x @ W_in^T + b_in + ctx[b]) -> bf16
    mfma_gemm<1, 1, 1><<<dim3(8, 128), 256, 0, stream>>>(
        x, W_in, b_in, ctx, nullptr, mixed, 1024, 1024);

    // 4-stage pipelined GRU section
    gru_pipe<<<256, 384, 0, stream>>>(
        Wih0, Whh0, bih0, bhh0, Wih1, Whh1, bih1, bhh1,
        mixed, h1, h2, xgs0, xgs1, flags);

    // out = (h2 * (1+gate)) @ W_out^T + b_out -> f32
    mfma_gemm<2, 1, 0><<<dim3(8, 128), 256, 0, stream>>>(
        h2, W_out, b_out, nullptr, gate, out, 1024, 1024);
}

// Round 12
// 2504.691 us; speedup vs baseline: 2.0133x; 1.7881x over previous
//
#include <hip/hip_runtime.h>
#include <cstdint>
#include <cstddef>

#define SEQT  512
#define HID   1024
#define G3    3072
#define HSTR  1048   // h_lds row stride in shorts (2096B: 16B-aligned, 2-way-free)
#define RING  32     // xgs ring depth
#define FSTR  32     // flag stride in u32 (128 B)

typedef __attribute__((ext_vector_type(8))) short bf16x8;
typedef __attribute__((ext_vector_type(8))) unsigned short u16x8;
typedef __attribute__((ext_vector_type(4))) float f32x4;

__device__ __forceinline__ float sigm(float x){ return 1.0f/(1.0f+expf(-x)); }
__device__ __forceinline__ float b2f(unsigned short s){ return __uint_as_float(((uint32_t)s)<<16); }
__device__ __forceinline__ unsigned short f2b(float f){
    uint32_t u=__float_as_uint(f);
    return (unsigned short)((u + 0x7FFFu + ((u>>16)&1u))>>16);
}

// ---------------------------------------------------------------------------
// MFMA GEMM (proven since R3). ASRC: 1=f32 reg-staged, 2=bf16 + (1+gate) fuse.
// BSRC: 1=f32 reg-staged. MODE: 0=f32+bias, 1=bf16 tanh(+bias+ctx).
// ---------------------------------------------------------------------------
template<int ASRC, int BSRC, int MODE>
__global__ __launch_bounds__(256) void mfma_gemm(
    const void* __restrict__ Av, const void* __restrict__ Bv,
    const float* __restrict__ bias, const float* __restrict__ ctx,
    const float* __restrict__ gate, void* __restrict__ Cv,
    int N, int K)
{
    __shared__ __align__(16) unsigned short As[128*64];
    __shared__ __align__(16) unsigned short Bs[128*64];
    const int tid = threadIdx.x;
    const int lane = tid & 63;
    const int w = tid >> 6;
    const int wm = w & 1, wn = w >> 1;
    const int m0 = blockIdx.y * 128, n0 = blockIdx.x * 128;

    f32x4 acc[4][4];
#pragma unroll
    for (int i = 0; i < 4; i++)
#pragma unroll
        for (int j = 0; j < 4; j++) acc[i][j] = (f32x4){0.f,0.f,0.f,0.f};

    for (int kt = 0; kt < K; kt += 64) {
        __syncthreads();
        if (ASRC == 1) {
            const float* Af = (const float*)Av;
#pragma unroll
            for (int p = 0; p < 4; p++) {
                const int q = p*256 + tid, row = q>>3, kc = q&7;
                const float* src = Af + (size_t)(m0+row)*K + kt + kc*8;
                float4 u = *(const float4*)src, v = *(const float4*)(src+4);
                __align__(16) unsigned short tmp[8] =
                    {f2b(u.x),f2b(u.y),f2b(u.z),f2b(u.w),f2b(v.x),f2b(v.y),f2b(v.z),f2b(v.w)};
                *(bf16x8*)&As[row*64 + kc*8] = *(const bf16x8*)tmp;
            }
        } else {
            const unsigned short* Ab = (const unsigned short*)Av;
#pragma unroll
            for (int p = 0; p < 4; p++) {
                const int q = p*256 + tid, row = q>>3, kc = q&7;
                const int b = (m0+row) >> 9;
                u16x8 hv = *(const u16x8*)(Ab + (size_t)(m0+row)*K + kt + kc*8);
                const float* gp = gate + (size_t)b*HID + kt + kc*8;
                float4 g0 = *(const float4*)gp, g1 = *(const float4*)(gp+4);
                const float gg[8] = {g0.x,g0.y,g0.z,g0.w,g1.x,g1.y,g1.z,g1.w};
                __align__(16) unsigned short tmp[8];
#pragma unroll
                for (int e = 0; e < 8; e++)
                    tmp[e] = f2b(b2f(hv[e]) * (1.0f + gg[e]));
                *(bf16x8*)&As[row*64 + kc*8] = *(const bf16x8*)tmp;
            }
        }
        {
            const float* Bf = (const float*)Bv;
#pragma unroll
            for (int p = 0; p < 4; p++) {
                const int q = p*256 + tid, row = q>>3, kc = q&7;
                const float* src = Bf + (size_t)(n0+row)*K + kt + kc*8;
                float4 u = *(const float4*)src, v = *(const float4*)(src+4);
                __align__(16) unsigned short tmp[8] =
                    {f2b(u.x),f2b(u.y),f2b(u.z),f2b(u.w),f2b(v.x),f2b(v.y),f2b(v.z),f2b(v.w)};
                *(bf16x8*)&Bs[row*64 + kc*8] = *(const bf16x8*)tmp;
            }
        }
        __syncthreads();
#pragma unroll
        for (int kg = 0; kg < 2; kg++) {
            bf16x8 af[4], bfr[4];
#pragma unroll
            for (int mi = 0; mi < 4; mi++)
                af[mi] = *(const bf16x8*)&As[(wm*64+mi*16+(lane&15))*64 + kg*32 + (lane>>4)*8];
#pragma unroll
            for (int ni = 0; ni < 4; ni++)
                bfr[ni] = *(const bf16x8*)&Bs[(wn*64+ni*16+(lane&15))*64 + kg*32 + (lane>>4)*8];
#pragma unroll
            for (int mi = 0; mi < 4; mi++)
#pragma unroll
                for (int ni = 0; ni < 4; ni++)
                    acc[mi][ni] = __builtin_amdgcn_mfma_f32_16x16x32_bf16(
                        af[mi], bfr[ni], acc[mi][ni], 0, 0, 0);
        }
    }

    const int cl = lane & 15, rg = lane >> 4;
    const int bct = m0 >> 9;
#pragma unroll
    for (int mi = 0; mi < 4; mi++) {
        const int rowb = m0 + wm*64 + mi*16 + rg*4;
#pragma unroll
        for (int ni = 0; ni < 4; ni++) {
            const int col = n0 + wn*64 + ni*16 + cl;
            const float bv = bias[col];
            const float cv = (MODE==1) ? ctx[(size_t)bct*HID + col] : 0.0f;
#pragma unroll
            for (int r = 0; r < 4; r++) {
                float val = acc[mi][ni][r] + bv;
                if (MODE==1) val = tanhf(val + cv);
                const size_t off = (size_t)(rowb+r)*N + col;
                if (MODE==0) ((float*)Cv)[off] = val;
                else ((unsigned short*)Cv)[off] = f2b(val);
            }
        }
    }
}

// ---------------------------------------------------------------------------
__global__ __launch_bounds__(256) void gate_kernel(
    const float* __restrict__ ctx, const float* __restrict__ Wg,
    const float* __restrict__ bg, float* __restrict__ gate)
{
    const int j = blockIdx.x * 256 + threadIdx.x;
    const int b = blockIdx.y;
    const float4* cp = (const float4*)(ctx + (size_t)b * HID);
    const float4* wp = (const float4*)(Wg + (size_t)j * HID);
    float acc = 0.0f;
#pragma unroll 4
    for (int k = 0; k < HID / 4; k++) {
        float4 c = cp[k], w = wp[k];
        acc += c.x * w.x + c.y * w.y + c.z * w.z + c.w * w.w;
    }
    gate[(size_t)b * HID + j] = sigm(acc + bg[j]);
}

__device__ __forceinline__ void poll_ge(const unsigned int* p, unsigned int tgt)
{
    while (__hip_atomic_load(p, __ATOMIC_RELAXED, __HIP_MEMORY_SCOPE_AGENT) < tgt)
        __builtin_amdgcn_s_sleep(2);
}

// ---------------------------------------------------------------------------
// 4-stage pipelined GRU (R7/R11 skeleton). This round:
//  * weight slice preloaded into 128 VGPRs/lane (loop-invariant, no LDS/step)
//  * h/input tile staged to LDS via global_load_lds (deep HW pipeline, no
//    VGPR round-trip, each line fetched once/block -> 3x traffic cut)
// ---------------------------------------------------------------------------
__global__ __launch_bounds__(384, 1) void gru_pipe(
    const float* __restrict__ Wih0, const float* __restrict__ Whh0,
    const float* __restrict__ bih0, const float* __restrict__ bhh0,
    const float* __restrict__ Wih1, const float* __restrict__ Whh1,
    const float* __restrict__ bih1, const float* __restrict__ bhh1,
    const unsigned short* __restrict__ mixed,   // [B*T][H] bf16
    unsigned short* __restrict__ h1,
    unsigned short* __restrict__ h2,
    unsigned short* __restrict__ xgs0,          // [64][RING][32][48] bf16
    unsigned short* __restrict__ xgs1,
    unsigned int* __restrict__ flags)           // 4 sets x 64 x FSTR u32
{
    __shared__ __align__(16) unsigned short h_lds[32*HSTR];
    __shared__ float sc[3][32][17];
    __shared__ uint32_t hlds[32][8];
    const int tid = threadIdx.x;
    const int lane = tid & 63;
    const int w = tid >> 6;
    const int bid = blockIdx.x;
    const int role = bid >> 6, rb = bid & 63;
    const int j0 = rb * 16;
    const int mh = w & 1, g = w >> 1;
    const int cl = lane & 15, kq = lane >> 4;

    unsigned int* fset[4] = { flags, flags + 64*FSTR, flags + 128*FSTR, flags + 192*FSTR };

    // ---- preload this lane's 32 weight B-fragments into registers --------
    const float* Wsrc = (role == 0) ? Wih0 : (role == 1) ? Whh0
                      : (role == 2) ? Wih1 : Whh1;
    bf16x8 wreg[32];
    {
        const float* wr = Wsrc + (size_t)(g*1024 + j0 + cl)*1024 + kq*8;
#pragma unroll
        for (int kg = 0; kg < 32; kg++) {
            float4 u = *(const float4*)(wr + (size_t)kg*32);
            float4 v = *(const float4*)(wr + (size_t)kg*32 + 4);
            __align__(16) unsigned short tmp[8] =
                {f2b(u.x),f2b(u.y),f2b(u.z),f2b(u.w),f2b(v.x),f2b(v.y),f2b(v.z),f2b(v.w)};
            wreg[kg] = *(const bf16x8*)tmp;
        }
    }

    const unsigned short* habase = &h_lds[(mh*16 + cl)*HSTR + kq*8];

    // stage 64KB tile (32 batches x 1024 shorts) of src[.][tt] into h_lds
    auto stage = [&](const unsigned short* src_base, int tt) {
        for (int c = w; c < 64; c += 6) {
            const int r = c >> 1, hf = c & 1;
            const unsigned short* src =
                src_base + ((size_t)r*SEQT + tt)*HID + hf*512 + lane*8;
            __builtin_amdgcn_global_load_lds(
                (const __attribute__((address_space(1))) void*)src,
                (__attribute__((address_space(3))) void*)&h_lds[r*HSTR + hf*512],
                16, 0, 0);
        }
    };

    if ((role & 1) == 0) {
        // ---------------- producer: xg = Wih @ hsrc[t] -------------------
        const unsigned short* hsrc = (role == 0) ? mixed : h1;
        unsigned short* xgs = ((role == 0) ? xgs0 : xgs1) + (size_t)rb*RING*32*48;
        const unsigned int* waitin = (role == 2) ? fset[1] : nullptr; // P1 waits R0
        const unsigned int* bp     = (role == 0) ? fset[1] : fset[3]; // consumer R
        unsigned int* myflag = &fset[role][rb*FSTR];

        for (int t = 0; t < SEQT; t++) {
            if (w == 0 && waitin)
                poll_ge(&waitin[lane*FSTR], (unsigned)(t+1));
            if (w == 1 && t >= RING && (t & 7) == 0)
                poll_ge(&bp[lane*FSTR], (unsigned)(t - 24));
            __syncthreads();

            stage(hsrc, t);
            asm volatile("s_waitcnt vmcnt(0)" ::: "memory");
            __syncthreads();

            f32x4 A[4];
#pragma unroll
            for (int i = 0; i < 4; i++) A[i] = (f32x4){0.f,0.f,0.f,0.f};
#pragma unroll
            for (int kg = 0; kg < 32; kg++) {
                bf16x8 hv = *(const bf16x8*)(habase + kg*32);
                A[kg & 3] = __builtin_amdgcn_mfma_f32_16x16x32_bf16(
                    hv, wreg[kg], A[kg & 3], 0, 0, 0);
            }
            f32x4 av = (A[0] + A[1]) + (A[2] + A[3]);
#pragma unroll
            for (int r = 0; r < 4; r++)
                sc[g][mh*16 + kq*4 + r][cl] = av[r];
            __syncthreads();

            if (tid < 192) {
                const int b = tid / 6, c16 = (tid % 6) * 8;
                unsigned short v[8];
#pragma unroll
                for (int k = 0; k < 8; k++) {
                    const int col = c16 + k;
                    v[k] = f2b(sc[col >> 4][b][col & 15]);
                }
                const uint64_t lo = (uint64_t)v[0] | ((uint64_t)v[1]<<16)
                                  | ((uint64_t)v[2]<<32) | ((uint64_t)v[3]<<48);
                const uint64_t hi = (uint64_t)v[4] | ((uint64_t)v[5]<<16)
                                  | ((uint64_t)v[6]<<32) | ((uint64_t)v[7]<<48);
                uint64_t* dst = (uint64_t*)(xgs + (((size_t)(t & (RING-1))*32 + b)*48 + c16));
                __hip_atomic_store(dst,   lo, __ATOMIC_RELAXED, __HIP_MEMORY_SCOPE_AGENT);
                __hip_atomic_store(dst+1, hi, __ATOMIC_RELAXED, __HIP_MEMORY_SCOPE_AGENT);
            }
            asm volatile("s_waitcnt vmcnt(0)" ::: "memory");
            __syncthreads();
            if (tid == 0)
                __hip_atomic_store(myflag, (unsigned)(t+1),
                                   __ATOMIC_RELAXED, __HIP_MEMORY_SCOPE_AGENT);
        }
    } else {
        // ---------------- recurrent: h[t] from xgs[t] + Whh@h[t-1] -------
        const unsigned short* xgs = ((role == 1) ? xgs0 : xgs1) + (size_t)rb*RING*32*48;
        unsigned short* hdst = (role == 1) ? h1 : h2;
        const float* bih = (role == 1) ? bih0 : bih1;
        const float* bhh = (role == 1) ? bhh0 : bhh1;
        const unsigned int* peers = fset[role];
        const unsigned int* prodf = &fset[role-1][rb*FSTR];
        unsigned int* myflag = &fset[role][rb*FSTR];

        const int fb = tid >> 3;
        const int fj = (tid & 7) * 2;
        float hp0 = 0.f, hp1 = 0.f;
        float br0=0,br1=0,bz0=0,bz1=0,bni0=0,bni1=0,bnh0=0,bnh1=0;
        if (tid < 256) {
            br0 = bih[j0+fj]        + bhh[j0+fj];
            br1 = bih[j0+fj+1]      + bhh[j0+fj+1];
            bz0 = bih[HID+j0+fj]    + bhh[HID+j0+fj];
            bz1 = bih[HID+j0+fj+1]  + bhh[HID+j0+fj+1];
            bni0 = bih[2*HID+j0+fj];   bni1 = bih[2*HID+j0+fj+1];
            bnh0 = bhh[2*HID+j0+fj];   bnh1 = bhh[2*HID+j0+fj+1];
        }

        for (int t = 0; t < SEQT; t++) {
            if (w == 0 && t > 0)
                poll_ge(&peers[lane*FSTR], (unsigned)t);
            if (w == 2 && lane == 0)
                poll_ge(prodf, (unsigned)(t+1));
            __syncthreads();

            if (t > 0) stage(hdst, t-1);

            uint32_t xr2=0, xz2=0, xn2=0;
            if (tid < 256) {
                const unsigned short* xp = xgs + ((size_t)(t & (RING-1))*32 + fb)*48;
                xr2 = __hip_atomic_load((const unsigned int*)(xp + fj),
                                        __ATOMIC_RELAXED, __HIP_MEMORY_SCOPE_AGENT);
                xz2 = __hip_atomic_load((const unsigned int*)(xp + 16 + fj),
                                        __ATOMIC_RELAXED, __HIP_MEMORY_SCOPE_AGENT);
                xn2 = __hip_atomic_load((const unsigned int*)(xp + 32 + fj),
                                        __ATOMIC_RELAXED, __HIP_MEMORY_SCOPE_AGENT);
            }
            asm volatile("s_waitcnt vmcnt(0)" ::: "memory");
            __syncthreads();

            f32x4 A[4];
#pragma unroll
            for (int i = 0; i < 4; i++) A[i] = (f32x4){0.f,0.f,0.f,0.f};
            if (t > 0) {
#pragma unroll
                for (int kg = 0; kg < 32; kg++) {
                    bf16x8 hv = *(const bf16x8*)(habase + kg*32);
                    A[kg & 3] = __builtin_amdgcn_mfma_f32_16x16x32_bf16(
                        hv, wreg[kg], A[kg & 3], 0, 0, 0);
                }
            }
            f32x4 av = (A[0] + A[1]) + (A[2] + A[3]);
#pragma unroll
            for (int r = 0; r < 4; r++)
                sc[g][mh*16 + kq*4 + r][cl] = av[r];
            __syncthreads();

            if (tid < 256) {
                const float r0 = sigm(b2f((unsigned short)(xr2 & 0xFFFF)) + sc[0][fb][fj]   + br0);
                const float r1 = sigm(b2f((unsigned short)(xr2 >> 16))    + sc[0][fb][fj+1] + br1);
                const float z0 = sigm(b2f((unsigned short)(xz2 & 0xFFFF)) + sc[1][fb][fj]   + bz0);
                const float z1 = sigm(b2f((unsigned short)(xz2 >> 16))    + sc[1][fb][fj+1] + bz1);
                const float n0 = tanhf(b2f((unsigned short)(xn2 & 0xFFFF)) + bni0
                                       + r0*(sc[2][fb][fj]   + bnh0));
                const float n1 = tanhf(b2f((unsigned short)(xn2 >> 16))    + bni1
                                       + r1*(sc[2][fb][fj+1] + bnh1));
                const float h0 = (1.0f - z0)*n0 + z0*hp0;
                const float h1v = (1.0f - z1)*n1 + z1*hp1;
                hp0 = h0; hp1 = h1v;
                hlds[fb][fj >> 1] = (uint32_t)f2b(h0) | ((uint32_t)f2b(h1v) << 16);
            }
            __syncthreads();

            if (w == 5) {
                const int pb = lane >> 1, ph = lane & 1;
                const uint32_t v0 = hlds[pb][ph*4 + 0];
                const uint32_t v1 = hlds[pb][ph*4 + 1];
                const uint32_t v2 = hlds[pb][ph*4 + 2];
                const uint32_t v3 = hlds[pb][ph*4 + 3];
                uint64_t* dst = (uint64_t*)(hdst + ((size_t)pb*SEQT + t)*HID + j0 + ph*8);
                __hip_atomic_store(dst,   (uint64_t)v0 | ((uint64_t)v1 << 32),
                                   __ATOMIC_RELAXED, __HIP_MEMORY_SCOPE_AGENT);
                __hip_atomic_store(dst+1, (uint64_t)v2 | ((uint64_t)v3 << 32),
                                   __ATOMIC_RELAXED, __HIP_MEMORY_SCOPE_AGENT);
                asm volatile("s_waitcnt vmcnt(0)" ::: "memory");
                if (lane == 0)
                    __hip_atomic_store(myflag, (unsigned)(t+1),
                                       __ATOMIC_RELAXED, __HIP_MEMORY_SCOPE_AGENT);
            }
        }
    }
}

// ---------------------------------------------------------------------------
__global__ __launch_bounds__(256) void diag_kernel(float* __restrict__ out,
                                                   int n, float code)
{
    for (int i = blockIdx.x * 256 + threadIdx.x; i < n; i += gridDim.x * 256)
        out[i] = (i == 0) ? code : 0.0f;
}

// ---------------------------------------------------------------------------
extern "C" void kernel_launch(void* const* d_in, const int* in_sizes, int n_in,
                              void* d_out, int out_size, void* d_ws, size_t ws_size,
                              hipStream_t stream)
{
    const float* x      = (const float*)d_in[0];
    const float* ctx    = (const float*)d_in[1];
    const float* W_in   = (const float*)d_in[2];
    const float* b_in   = (const float*)d_in[3];
    const float* Wih0   = (const float*)d_in[4];
    const float* Whh0   = (const float*)d_in[5];
    const float* bih0   = (const float*)d_in[6];
    const float* bhh0   = (const float*)d_in[7];
    const float* Wih1   = (const float*)d_in[8];
    const float* Whh1   = (const float*)d_in[9];
    const float* bih1   = (const float*)d_in[10];
    const float* bhh1   = (const float*)d_in[11];
    const float* W_out  = (const float*)d_in[12];
    const float* b_out  = (const float*)d_in[13];
    const float* W_gate = (const float*)d_in[14];
    const float* b_gate = (const float*)d_in[15];
    float* out = (float*)d_out;

    const size_t MX = (size_t)16384 * 1024 * 2;                 // 32 MiB
    const size_t XS = (size_t)64 * RING * 32 * 48 * 2;          // 6 MiB
    const size_t GT = (size_t)32 * 1024 * 4;
    const size_t FL = (size_t)4 * 64 * FSTR * 4;                // 32 KiB
    const size_t need = 3*MX + 2*XS + GT + FL;

    if (ws_size < need) {
        diag_kernel<<<2048, 256, 0, stream>>>(out, out_size, (float)(ws_size >> 20));
        return;
    }

    char* ws = (char*)d_ws;
    unsigned short* mixed = (unsigned short*)ws;
    unsigned short* h1    = (unsigned short*)(ws + MX);
    unsigned short* h2    = (unsigned short*)(ws + 2*MX);
    unsigned short* xgs0  = (unsigned short*)(ws + 3*MX);
    unsigned short* xgs1  = (unsigned short*)(ws + 3*MX + XS);
    float*          gate  = (float*)(ws + 3*MX + 2*XS);
    unsigned int*   flags = (unsigned int*)(ws + 3*MX + 2*XS + GT);

    hipMemsetAsync(flags, 0, FL, stream);
    gate_kernel<<<dim3(4, 32), 256, 0, stream>>>(ctx, W_gate, b_gate, gate);

    // mixed = tanh(x @ W_in^T + b_in + ctx[b]) -> bf16
    mfma_gemm<1, 1, 1><<<dim3(8, 128), 256, 0, stream>>>(
        x, W_in, b_in, ctx, nullptr, mixed, 1024, 1024);

    // 4-stage pipelined GRU section
    gru_pipe<<<256, 384, 0, stream>>>(
        Wih0, Whh0, bih0, bhh0, Wih1, Whh1, bih1, bhh1,
        mixed, h1, h2, xgs0, xgs1, flags);

    // out = (h2 * (1+gate)) @ W_out^T + b_out -> f32
    mfma_gemm<2, 1, 0><<<dim3(8, 128), 256, 0, stream>>>(
        h2, W_out, b_out, nullptr, gate, out, 1024, 1024);
}

// Round 13
// 2389.884 us; speedup vs baseline: 2.1100x; 1.0480x over previous
//
#include <hip/hip_runtime.h>
#include <cstdint>
#include <cstddef>

#define SEQT  512
#define HID   1024
#define G3    3072
#define HSTR  1080   // h_lds row stride in shorts (2160 B, 16B-aligned)
#define RING  32     // xgs ring depth
#define FSTR  32     // flag stride in u32 (128 B)

typedef __attribute__((ext_vector_type(8))) short bf16x8;
typedef __attribute__((ext_vector_type(8))) unsigned short u16x8;
typedef __attribute__((ext_vector_type(4))) float f32x4;

__device__ __forceinline__ float sigm(float x){ return 1.0f/(1.0f+expf(-x)); }
__device__ __forceinline__ float b2f(unsigned short s){ return __uint_as_float(((uint32_t)s)<<16); }
__device__ __forceinline__ unsigned short f2b(float f){
    uint32_t u=__float_as_uint(f);
    return (unsigned short)((u + 0x7FFFu + ((u>>16)&1u))>>16);
}

// ---------------------------------------------------------------------------
// MFMA GEMM (proven since R3). ASRC: 1=f32 reg-staged, 2=bf16 + (1+gate) fuse.
// BSRC: 1=f32 reg-staged. MODE: 0=f32+bias, 1=bf16 tanh(+bias+ctx).
// ---------------------------------------------------------------------------
template<int ASRC, int BSRC, int MODE>
__global__ __launch_bounds__(256) void mfma_gemm(
    const void* __restrict__ Av, const void* __restrict__ Bv,
    const float* __restrict__ bias, const float* __restrict__ ctx,
    const float* __restrict__ gate, void* __restrict__ Cv,
    int N, int K)
{
    __shared__ __align__(16) unsigned short As[128*64];
    __shared__ __align__(16) unsigned short Bs[128*64];
    const int tid = threadIdx.x;
    const int lane = tid & 63;
    const int w = tid >> 6;
    const int wm = w & 1, wn = w >> 1;
    const int m0 = blockIdx.y * 128, n0 = blockIdx.x * 128;

    f32x4 acc[4][4];
#pragma unroll
    for (int i = 0; i < 4; i++)
#pragma unroll
        for (int j = 0; j < 4; j++) acc[i][j] = (f32x4){0.f,0.f,0.f,0.f};

    for (int kt = 0; kt < K; kt += 64) {
        __syncthreads();
        if (ASRC == 1) {
            const float* Af = (const float*)Av;
#pragma unroll
            for (int p = 0; p < 4; p++) {
                const int q = p*256 + tid, row = q>>3, kc = q&7;
                const float* src = Af + (size_t)(m0+row)*K + kt + kc*8;
                float4 u = *(const float4*)src, v = *(const float4*)(src+4);
                __align__(16) unsigned short tmp[8] =
                    {f2b(u.x),f2b(u.y),f2b(u.z),f2b(u.w),f2b(v.x),f2b(v.y),f2b(v.z),f2b(v.w)};
                *(bf16x8*)&As[row*64 + kc*8] = *(const bf16x8*)tmp;
            }
        } else {
            const unsigned short* Ab = (const unsigned short*)Av;
#pragma unroll
            for (int p = 0; p < 4; p++) {
                const int q = p*256 + tid, row = q>>3, kc = q&7;
                const int b = (m0+row) >> 9;
                u16x8 hv = *(const u16x8*)(Ab + (size_t)(m0+row)*K + kt + kc*8);
                const float* gp = gate + (size_t)b*HID + kt + kc*8;
                float4 g0 = *(const float4*)gp, g1 = *(const float4*)(gp+4);
                const float gg[8] = {g0.x,g0.y,g0.z,g0.w,g1.x,g1.y,g1.z,g1.w};
                __align__(16) unsigned short tmp[8];
#pragma unroll
                for (int e = 0; e < 8; e++)
                    tmp[e] = f2b(b2f(hv[e]) * (1.0f + gg[e]));
                *(bf16x8*)&As[row*64 + kc*8] = *(const bf16x8*)tmp;
            }
        }
        {
            const float* Bf = (const float*)Bv;
#pragma unroll
            for (int p = 0; p < 4; p++) {
                const int q = p*256 + tid, row = q>>3, kc = q&7;
                const float* src = Bf + (size_t)(n0+row)*K + kt + kc*8;
                float4 u = *(const float4*)src, v = *(const float4*)(src+4);
                __align__(16) unsigned short tmp[8] =
                    {f2b(u.x),f2b(u.y),f2b(u.z),f2b(u.w),f2b(v.x),f2b(v.y),f2b(v.z),f2b(v.w)};
                *(bf16x8*)&Bs[row*64 + kc*8] = *(const bf16x8*)tmp;
            }
        }
        __syncthreads();
#pragma unroll
        for (int kg = 0; kg < 2; kg++) {
            bf16x8 af[4], bfr[4];
#pragma unroll
            for (int mi = 0; mi < 4; mi++)
                af[mi] = *(const bf16x8*)&As[(wm*64+mi*16+(lane&15))*64 + kg*32 + (lane>>4)*8];
#pragma unroll
            for (int ni = 0; ni < 4; ni++)
                bfr[ni] = *(const bf16x8*)&Bs[(wn*64+ni*16+(lane&15))*64 + kg*32 + (lane>>4)*8];
#pragma unroll
            for (int mi = 0; mi < 4; mi++)
#pragma unroll
                for (int ni = 0; ni < 4; ni++)
                    acc[mi][ni] = __builtin_amdgcn_mfma_f32_16x16x32_bf16(
                        af[mi], bfr[ni], acc[mi][ni], 0, 0, 0);
        }
    }

    const int cl = lane & 15, rg = lane >> 4;
    const int bct = m0 >> 9;
#pragma unroll
    for (int mi = 0; mi < 4; mi++) {
        const int rowb = m0 + wm*64 + mi*16 + rg*4;
#pragma unroll
        for (int ni = 0; ni < 4; ni++) {
            const int col = n0 + wn*64 + ni*16 + cl;
            const float bv = bias[col];
            const float cv = (MODE==1) ? ctx[(size_t)bct*HID + col] : 0.0f;
#pragma unroll
            for (int r = 0; r < 4; r++) {
                float val = acc[mi][ni][r] + bv;
                if (MODE==1) val = tanhf(val + cv);
                const size_t off = (size_t)(rowb+r)*N + col;
                if (MODE==0) ((float*)Cv)[off] = val;
                else ((unsigned short*)Cv)[off] = f2b(val);
            }
        }
    }
}

// ---------------------------------------------------------------------------
__global__ __launch_bounds__(256) void gate_kernel(
    const float* __restrict__ ctx, const float* __restrict__ Wg,
    const float* __restrict__ bg, float* __restrict__ gate)
{
    const int j = blockIdx.x * 256 + threadIdx.x;
    const int b = blockIdx.y;
    const float4* cp = (const float4*)(ctx + (size_t)b * HID);
    const float4* wp = (const float4*)(Wg + (size_t)j * HID);
    float acc = 0.0f;
#pragma unroll 4
    for (int k = 0; k < HID / 4; k++) {
        float4 c = cp[k], w = wp[k];
        acc += c.x * w.x + c.y * w.y + c.z * w.z + c.w * w.w;
    }
    gate[(size_t)b * HID + j] = sigm(acc + bg[j]);
}

__device__ __forceinline__ void poll_ge(const unsigned int* p, unsigned int tgt)
{
    while (__hip_atomic_load(p, __ATOMIC_RELAXED, __HIP_MEMORY_SCOPE_AGENT) < tgt)
        __builtin_amdgcn_s_sleep(2);
}

// ---------------------------------------------------------------------------
// 4-stage pipelined GRU (R12 winner). This round:
//  * wreg PINNED live via asm "+v" (R12: compiler sank loads -> 196KB/step L2
//    weight re-fetch; VGPR tell 96 -> expect ~230+)
//  * bank-phase rotation: HSTR=1080 + rot(r)=(r&3)*32B on stage dest & read
//    base -> quad-start = 4*((r+kq)%8): uniform 8 lanes/quad (b128 optimum)
//  * direct publish from finalize threads (no hlds/w5 hop)
// ---------------------------------------------------------------------------
__global__ __launch_bounds__(384, 1) void gru_pipe(
    const float* __restrict__ Wih0, const float* __restrict__ Whh0,
    const float* __restrict__ bih0, const float* __restrict__ bhh0,
    const float* __restrict__ Wih1, const float* __restrict__ Whh1,
    const float* __restrict__ bih1, const float* __restrict__ bhh1,
    const unsigned short* __restrict__ mixed,   // [B*T][H] bf16
    unsigned short* __restrict__ h1,
    unsigned short* __restrict__ h2,
    unsigned short* __restrict__ xgs0,          // [64][RING][32][48] bf16
    unsigned short* __restrict__ xgs1,
    unsigned int* __restrict__ flags)           // 4 sets x 64 x FSTR u32
{
    __shared__ __align__(16) unsigned short h_lds[32*HSTR];
    __shared__ float sc[3][32][17];
    const int tid = threadIdx.x;
    const int lane = tid & 63;
    const int w = tid >> 6;
    const int bid = blockIdx.x;
    const int role = bid >> 6, rb = bid & 63;
    const int j0 = rb * 16;
    const int mh = w & 1, g = w >> 1;
    const int cl = lane & 15, kq = lane >> 4;

    unsigned int* fset[4] = { flags, flags + 64*FSTR, flags + 128*FSTR, flags + 192*FSTR };

    // ---- preload this lane's 32 weight B-fragments into registers --------
    const float* Wsrc = (role == 0) ? Wih0 : (role == 1) ? Whh0
                      : (role == 2) ? Wih1 : Whh1;
    bf16x8 wreg[32];
    {
        const float* wr = Wsrc + (size_t)(g*1024 + j0 + cl)*1024 + kq*8;
#pragma unroll
        for (int kg = 0; kg < 32; kg++) {
            float4 u = *(const float4*)(wr + (size_t)kg*32);
            float4 v = *(const float4*)(wr + (size_t)kg*32 + 4);
            __align__(16) unsigned short tmp[8] =
                {f2b(u.x),f2b(u.y),f2b(u.z),f2b(u.w),f2b(v.x),f2b(v.y),f2b(v.z),f2b(v.w)};
            wreg[kg] = *(const bf16x8*)tmp;
        }
    }
    // pin: asm def makes each wreg value live across the t-loop; the feeding
    // loads cannot sink into the loop (R12 failure mode).
#pragma unroll
    for (int kg = 0; kg < 32; kg++)
        asm volatile("" : "+v"(wreg[kg]));

    // read base: row = mh*16+cl, byte = row*2160 + (row&3)*32 + kq*16
    const int hrow_r = mh*16 + cl;
    const unsigned short* habase =
        &h_lds[hrow_r*HSTR + ((hrow_r & 3) << 4) + kq*8];

    // stage 64KB tile (32 batches x 1024 shorts) of src[.][tt] into h_lds
    auto stage = [&](const unsigned short* src_base, int tt) {
        for (int c = w; c < 64; c += 6) {
            const int r = c >> 1, hf = c & 1;
            const unsigned short* src =
                src_base + ((size_t)r*SEQT + tt)*HID + hf*512 + lane*8;
            __builtin_amdgcn_global_load_lds(
                (const __attribute__((address_space(1))) void*)src,
                (__attribute__((address_space(3))) void*)
                    &h_lds[r*HSTR + ((r & 3) << 4) + hf*512],
                16, 0, 0);
        }
    };

    if ((role & 1) == 0) {
        // ---------------- producer: xg = Wih @ hsrc[t] -------------------
        const unsigned short* hsrc = (role == 0) ? mixed : h1;
        unsigned short* xgs = ((role == 0) ? xgs0 : xgs1) + (size_t)rb*RING*32*48;
        const unsigned int* waitin = (role == 2) ? fset[1] : nullptr; // P1 waits R0
        const unsigned int* bp     = (role == 0) ? fset[1] : fset[3]; // consumer R
        unsigned int* myflag = &fset[role][rb*FSTR];

        for (int t = 0; t < SEQT; t++) {
            if (w == 0 && waitin)
                poll_ge(&waitin[lane*FSTR], (unsigned)(t+1));
            if (w == 1 && t >= RING && (t & 7) == 0)
                poll_ge(&bp[lane*FSTR], (unsigned)(t - 24));
            __syncthreads();

            stage(hsrc, t);
            asm volatile("s_waitcnt vmcnt(0)" ::: "memory");
            __syncthreads();

            f32x4 A[4];
#pragma unroll
            for (int i = 0; i < 4; i++) A[i] = (f32x4){0.f,0.f,0.f,0.f};
#pragma unroll
            for (int kg = 0; kg < 32; kg++) {
                bf16x8 hv = *(const bf16x8*)(habase + kg*32);
                A[kg & 3] = __builtin_amdgcn_mfma_f32_16x16x32_bf16(
                    hv, wreg[kg], A[kg & 3], 0, 0, 0);
            }
            f32x4 av = (A[0] + A[1]) + (A[2] + A[3]);
#pragma unroll
            for (int r = 0; r < 4; r++)
                sc[g][mh*16 + kq*4 + r][cl] = av[r];
            __syncthreads();

            if (tid < 192) {
                const int b = tid / 6, c16 = (tid % 6) * 8;
                unsigned short v[8];
#pragma unroll
                for (int k = 0; k < 8; k++) {
                    const int col = c16 + k;
                    v[k] = f2b(sc[col >> 4][b][col & 15]);
                }
                const uint64_t lo = (uint64_t)v[0] | ((uint64_t)v[1]<<16)
                                  | ((uint64_t)v[2]<<32) | ((uint64_t)v[3]<<48);
                const uint64_t hi = (uint64_t)v[4] | ((uint64_t)v[5]<<16)
                                  | ((uint64_t)v[6]<<32) | ((uint64_t)v[7]<<48);
                uint64_t* dst = (uint64_t*)(xgs + (((size_t)(t & (RING-1))*32 + b)*48 + c16));
                __hip_atomic_store(dst,   lo, __ATOMIC_RELAXED, __HIP_MEMORY_SCOPE_AGENT);
                __hip_atomic_store(dst+1, hi, __ATOMIC_RELAXED, __HIP_MEMORY_SCOPE_AGENT);
            }
            asm volatile("s_waitcnt vmcnt(0)" ::: "memory");
            __syncthreads();
            if (tid == 0)
                __hip_atomic_store(myflag, (unsigned)(t+1),
                                   __ATOMIC_RELAXED, __HIP_MEMORY_SCOPE_AGENT);
        }
    } else {
        // ---------------- recurrent: h[t] from xgs[t] + Whh@h[t-1] -------
        const unsigned short* xgs = ((role == 1) ? xgs0 : xgs1) + (size_t)rb*RING*32*48;
        unsigned short* hdst = (role == 1) ? h1 : h2;
        const float* bih = (role == 1) ? bih0 : bih1;
        const float* bhh = (role == 1) ? bhh0 : bhh1;
        const unsigned int* peers = fset[role];
        const unsigned int* prodf = &fset[role-1][rb*FSTR];
        unsigned int* myflag = &fset[role][rb*FSTR];

        const int fb = tid >> 3;
        const int fj = (tid & 7) * 2;
        float hp0 = 0.f, hp1 = 0.f;
        float br0=0,br1=0,bz0=0,bz1=0,bni0=0,bni1=0,bnh0=0,bnh1=0;
        if (tid < 256) {
            br0 = bih[j0+fj]        + bhh[j0+fj];
            br1 = bih[j0+fj+1]      + bhh[j0+fj+1];
            bz0 = bih[HID+j0+fj]    + bhh[HID+j0+fj];
            bz1 = bih[HID+j0+fj+1]  + bhh[HID+j0+fj+1];
            bni0 = bih[2*HID+j0+fj];   bni1 = bih[2*HID+j0+fj+1];
            bnh0 = bhh[2*HID+j0+fj];   bnh1 = bhh[2*HID+j0+fj+1];
        }

        for (int t = 0; t < SEQT; t++) {
            if (w == 0 && t > 0)
                poll_ge(&peers[lane*FSTR], (unsigned)t);
            if (w == 2 && lane == 0)
                poll_ge(prodf, (unsigned)(t+1));
            __syncthreads();

            if (t > 0) stage(hdst, t-1);

            uint32_t xr2=0, xz2=0, xn2=0;
            if (tid < 256) {
                const unsigned short* xp = xgs + ((size_t)(t & (RING-1))*32 + fb)*48;
                xr2 = __hip_atomic_load((const unsigned int*)(xp + fj),
                                        __ATOMIC_RELAXED, __HIP_MEMORY_SCOPE_AGENT);
                xz2 = __hip_atomic_load((const unsigned int*)(xp + 16 + fj),
                                        __ATOMIC_RELAXED, __HIP_MEMORY_SCOPE_AGENT);
                xn2 = __hip_atomic_load((const unsigned int*)(xp + 32 + fj),
                                        __ATOMIC_RELAXED, __HIP_MEMORY_SCOPE_AGENT);
            }
            asm volatile("s_waitcnt vmcnt(0)" ::: "memory");
            __syncthreads();

            f32x4 A[4];
#pragma unroll
            for (int i = 0; i < 4; i++) A[i] = (f32x4){0.f,0.f,0.f,0.f};
            if (t > 0) {
#pragma unroll
                for (int kg = 0; kg < 32; kg++) {
                    bf16x8 hv = *(const bf16x8*)(habase + kg*32);
                    A[kg & 3] = __builtin_amdgcn_mfma_f32_16x16x32_bf16(
                        hv, wreg[kg], A[kg & 3], 0, 0, 0);
                }
            }
            f32x4 av = (A[0] + A[1]) + (A[2] + A[3]);
#pragma unroll
            for (int r = 0; r < 4; r++)
                sc[g][mh*16 + kq*4 + r][cl] = av[r];
            __syncthreads();

            if (tid < 256) {
                const float r0 = sigm(b2f((unsigned short)(xr2 & 0xFFFF)) + sc[0][fb][fj]   + br0);
                const float r1 = sigm(b2f((unsigned short)(xr2 >> 16))    + sc[0][fb][fj+1] + br1);
                const float z0 = sigm(b2f((unsigned short)(xz2 & 0xFFFF)) + sc[1][fb][fj]   + bz0);
                const float z1 = sigm(b2f((unsigned short)(xz2 >> 16))    + sc[1][fb][fj+1] + bz1);
                const float n0 = tanhf(b2f((unsigned short)(xn2 & 0xFFFF)) + bni0
                                       + r0*(sc[2][fb][fj]   + bnh0));
                const float n1 = tanhf(b2f((unsigned short)(xn2 >> 16))    + bni1
                                       + r1*(sc[2][fb][fj+1] + bnh1));
                const float h0 = (1.0f - z0)*n0 + z0*hp0;
                const float h1v = (1.0f - z1)*n1 + z1*hp1;
                hp0 = h0; hp1 = h1v;
                // direct publish (agent-scope write-through, R5-proven form)
                const uint32_t hv = (uint32_t)f2b(h0) | ((uint32_t)f2b(h1v) << 16);
                uint32_t* dst = (uint32_t*)(hdst + ((size_t)fb*SEQT + t)*HID + j0 + fj);
                __hip_atomic_store(dst, hv, __ATOMIC_RELAXED, __HIP_MEMORY_SCOPE_AGENT);
            }
            asm volatile("s_waitcnt vmcnt(0)" ::: "memory");
            __syncthreads();
            if (tid == 0)
                __hip_atomic_store(myflag, (unsigned)(t+1),
                                   __ATOMIC_RELAXED, __HIP_MEMORY_SCOPE_AGENT);
        }
    }
}

// ---------------------------------------------------------------------------
__global__ __launch_bounds__(256) void diag_kernel(float* __restrict__ out,
                                                   int n, float code)
{
    for (int i = blockIdx.x * 256 + threadIdx.x; i < n; i += gridDim.x * 256)
        out[i] = (i == 0) ? code : 0.0f;
}

// ---------------------------------------------------------------------------
extern "C" void kernel_launch(void* const* d_in, const int* in_sizes, int n_in,
                              void* d_out, int out_size, void* d_ws, size_t ws_size,
                              hipStream_t stream)
{
    const float* x      = (const float*)d_in[0];
    const float* ctx    = (const float*)d_in[1];
    const float* W_in   = (const float*)d_in[2];
    const float* b_in   = (const float*)d_in[3];
    const float* Wih0   = (const float*)d_in[4];
    const float* Whh0   = (const float*)d_in[5];
    const float* bih0   = (const float*)d_in[6];
    const float* bhh0   = (const float*)d_in[7];
    const float* Wih1   = (const float*)d_in[8];
    const float* Whh1   = (const float*)d_in[9];
    const float* bih1   = (const float*)d_in[10];
    const float* bhh1   = (const float*)d_in[11];
    const float* W_out  = (const float*)d_in[12];
    const float* b_out  = (const float*)d_in[13];
    const float* W_gate = (const float*)d_in[14];
    const float* b_gate = (const float*)d_in[15];
    float* out = (float*)d_out;

    const size_t MX = (size_t)16384 * 1024 * 2;                 // 32 MiB
    const size_t XS = (size_t)64 * RING * 32 * 48 * 2;          // 6 MiB
    const size_t GT = (size_t)32 * 1024 * 4;
    const size_t FL = (size_t)4 * 64 * FSTR * 4;                // 32 KiB
    const size_t need = 3*MX + 2*XS + GT + FL;

    if (ws_size < need) {
        diag_kernel<<<2048, 256, 0, stream>>>(out, out_size, (float)(ws_size >> 20));
        return;
    }

    char* ws = (char*)d_ws;
    unsigned short* mixed = (unsigned short*)ws;
    unsigned short* h1    = (unsigned short*)(ws + MX);
    unsigned short* h2    = (unsigned short*)(ws + 2*MX);
    unsigned short* xgs0  = (unsigned short*)(ws + 3*MX);
    unsigned short* xgs1  = (unsigned short*)(ws + 3*MX + XS);
    float*          gate  = (float*)(ws + 3*MX + 2*XS);
    unsigned int*   flags = (unsigned int*)(ws + 3*MX + 2*XS + GT);

    hipMemsetAsync(flags, 0, FL, stream);
    gate_kernel<<<dim3(4, 32), 256, 0, stream>>>(ctx, W_gate, b_gate, gate);

    // mixed = tanh(x @ W_in^T + b_in + ctx[b]) -> bf16
    mfma_gemm<1, 1, 1><<<dim3(8, 128), 256, 0, stream>>>(
        x, W_in, b_in, ctx, nullptr, mixed, 1024, 1024);

    // 4-stage pipelined GRU section
    gru_pipe<<<256, 384, 0, stream>>>(
        Wih0, Whh0, bih0, bhh0, Wih1, Whh1, bih1, bhh1,
        mixed, h1, h2, xgs0, xgs1, flags);

    // out = (h2 * (1+gate)) @ W_out^T + b_out -> f32
    mfma_gemm<2, 1, 0><<<dim3(8, 128), 256, 0, stream>>>(
        h2, W_out, b_out, nullptr, gate, out, 1024, 1024);
}